// Round 1
// baseline (352.008 us; speedup 1.0000x reference)
//
#include <hip/hip_runtime.h>
#include <hip/hip_bf16.h>
#include <math.h>

#define BLOCK 256
#define WAVES_PER_BLOCK (BLOCK / 64)
#define GRID1 2048

// Kernel 1: one wave per row (grid-stride over rows). Each wave computes
// max_{j != y}(pred[row][j]), then hinge = max(0, max - pred[row][y] + 1).
// Per-block partial sums go to d_ws.
__global__ __launch_bounds__(BLOCK) void hinge_rows_kernel(
    const float* __restrict__ pred, const int* __restrict__ target,
    float* __restrict__ partial, int B, int C) {
  const int lane = threadIdx.x & 63;
  const int wave = threadIdx.x >> 6;
  const int gwave = blockIdx.x * WAVES_PER_BLOCK + wave;
  const int nwaves = gridDim.x * WAVES_PER_BLOCK;
  const int nvec = C >> 2;  // float4 chunks per row

  float sum = 0.0f;

  for (int row = gwave; row < B; row += nwaves) {
    const float* rp = pred + (size_t)row * (size_t)C;
    const int y = target[row];
    // all 64 lanes read the same address -> HW broadcast, 1 transaction
    const float correct = rp[y];

    float m = -INFINITY;
    const float4* rp4 = (const float4*)rp;  // row byte offset = row*4000, 16B aligned
    for (int i = lane; i < nvec; i += 64) {
      float4 v = rp4[i];
      const int base = i << 2;
      // branchless mask of the true class (one cndmask per element)
      v.x = (base + 0 == y) ? -INFINITY : v.x;
      v.y = (base + 1 == y) ? -INFINITY : v.y;
      v.z = (base + 2 == y) ? -INFINITY : v.z;
      v.w = (base + 3 == y) ? -INFINITY : v.w;
      m = fmaxf(m, fmaxf(fmaxf(v.x, v.y), fmaxf(v.z, v.w)));
    }
    // scalar tail if C % 4 != 0 (C=1000 -> no-op)
    for (int c = (nvec << 2) + lane; c < C; c += 64) {
      if (c != y) m = fmaxf(m, rp[c]);
    }

    // 64-lane butterfly max -> all lanes hold row max
    #pragma unroll
    for (int off = 32; off; off >>= 1)
      m = fmaxf(m, __shfl_xor(m, off));

    sum += fmaxf(m - correct + 1.0f, 0.0f);
  }

  // sum is identical across the wave's lanes; lane 0 represents the wave
  __shared__ float lsum[WAVES_PER_BLOCK];
  if (lane == 0) lsum[wave] = sum;
  __syncthreads();
  if (threadIdx.x == 0) {
    float s = 0.0f;
    #pragma unroll
    for (int w = 0; w < WAVES_PER_BLOCK; ++w) s += lsum[w];
    partial[blockIdx.x] = s;
  }
}

// Kernel 2: reduce GRID1 partials, scale by 1/B, write scalar output.
__global__ __launch_bounds__(BLOCK) void hinge_reduce_kernel(
    const float* __restrict__ partial, int n, float* __restrict__ out,
    float scale) {
  float s = 0.0f;
  for (int i = threadIdx.x; i < n; i += BLOCK) s += partial[i];

  #pragma unroll
  for (int off = 32; off; off >>= 1) s += __shfl_xor(s, off);

  const int lane = threadIdx.x & 63;
  const int wave = threadIdx.x >> 6;
  __shared__ float lsum[WAVES_PER_BLOCK];
  if (lane == 0) lsum[wave] = s;
  __syncthreads();
  if (threadIdx.x == 0) {
    float t = 0.0f;
    #pragma unroll
    for (int w = 0; w < WAVES_PER_BLOCK; ++w) t += lsum[w];
    out[0] = t * scale;
  }
}

extern "C" void kernel_launch(void* const* d_in, const int* in_sizes, int n_in,
                              void* d_out, int out_size, void* d_ws, size_t ws_size,
                              hipStream_t stream) {
  const float* pred = (const float*)d_in[0];
  const int* target = (const int*)d_in[1];
  float* out = (float*)d_out;
  float* partial = (float*)d_ws;

  const int B = in_sizes[1];
  const int C = in_sizes[0] / B;

  hinge_rows_kernel<<<GRID1, BLOCK, 0, stream>>>(pred, target, partial, B, C);
  hinge_reduce_kernel<<<1, BLOCK, 0, stream>>>(partial, GRID1, out, 1.0f / (float)B);
}

// Round 2
// 349.904 us; speedup vs baseline: 1.0060x; 1.0060x over previous
//
#include <hip/hip_runtime.h>
#include <hip/hip_bf16.h>
#include <math.h>

#define BLOCK 256
#define WAVES_PER_BLOCK (BLOCK / 64)
#define GRID1 2048

typedef float f32x4 __attribute__((ext_vector_type(4)));

// Kernel 1: one wave per 8 consecutive rows. Prologue batch-loads the wave's
// 8 targets (1 vector load, lanes 0..7) and 8 correct-class scores (1 vector
// gather, 8 addresses in flight) -- removes the per-row serialized scalar-load
// dependency chain. Row data streamed with non-temporal float4 loads
// (262 MB > L3, zero reuse).
__global__ __launch_bounds__(BLOCK) void hinge_rows_kernel(
    const float* __restrict__ pred, const int* __restrict__ target,
    float* __restrict__ partial, int B, int C) {
  const int lane = threadIdx.x & 63;
  const int wave = threadIdx.x >> 6;
  const int gwave = blockIdx.x * WAVES_PER_BLOCK + wave;
  const int nwaves = gridDim.x * WAVES_PER_BLOCK;
  const int rpw = (B + nwaves - 1) / nwaves;  // rows per wave (8 at B=65536)
  const int base = gwave * rpw;
  const int nvec = C >> 2;

  // Prefetch this wave's targets + correct scores: lane l owns row base+l.
  int ty = 0;
  float corr = 0.0f;
  if (lane < rpw && base + lane < B) {
    ty = target[base + lane];
    corr = pred[(size_t)(base + lane) * (size_t)C + ty];
  }

  float sum = 0.0f;

  for (int k = 0; k < rpw; ++k) {
    const int row = base + k;
    if (row >= B) break;
    const int y = __shfl(ty, k);
    const float correct = __shfl(corr, k);

    const float* rp = pred + (size_t)row * (size_t)C;
    const f32x4* rp4 = (const f32x4*)rp;

    float m = -INFINITY;
    #pragma unroll 4
    for (int i = lane; i < nvec; i += 64) {
      f32x4 v = __builtin_nontemporal_load(&rp4[i]);
      const int b0 = i << 2;
      v.x = (b0 + 0 == y) ? -INFINITY : v.x;
      v.y = (b0 + 1 == y) ? -INFINITY : v.y;
      v.z = (b0 + 2 == y) ? -INFINITY : v.z;
      v.w = (b0 + 3 == y) ? -INFINITY : v.w;
      m = fmaxf(m, fmaxf(fmaxf(v.x, v.y), fmaxf(v.z, v.w)));
    }
    // scalar tail if C % 4 != 0 (C=1000 -> no-op)
    for (int c = (nvec << 2) + lane; c < C; c += 64) {
      if (c != y) m = fmaxf(m, rp[c]);
    }

    // 64-lane butterfly max -> all lanes hold the row max
    #pragma unroll
    for (int off = 32; off; off >>= 1)
      m = fmaxf(m, __shfl_xor(m, off));

    sum += fmaxf(m - correct + 1.0f, 0.0f);
  }

  // sum is identical across the wave's lanes; lane 0 represents the wave
  __shared__ float lsum[WAVES_PER_BLOCK];
  if (lane == 0) lsum[wave] = sum;
  __syncthreads();
  if (threadIdx.x == 0) {
    float s = 0.0f;
    #pragma unroll
    for (int w = 0; w < WAVES_PER_BLOCK; ++w) s += lsum[w];
    partial[blockIdx.x] = s;
  }
}

// Kernel 2: reduce GRID1 partials, scale by 1/B, write scalar output.
__global__ __launch_bounds__(BLOCK) void hinge_reduce_kernel(
    const float* __restrict__ partial, int n, float* __restrict__ out,
    float scale) {
  float s = 0.0f;
  for (int i = threadIdx.x; i < n; i += BLOCK) s += partial[i];

  #pragma unroll
  for (int off = 32; off; off >>= 1) s += __shfl_xor(s, off);

  const int lane = threadIdx.x & 63;
  const int wave = threadIdx.x >> 6;
  __shared__ float lsum[WAVES_PER_BLOCK];
  if (lane == 0) lsum[wave] = s;
  __syncthreads();
  if (threadIdx.x == 0) {
    float t = 0.0f;
    #pragma unroll
    for (int w = 0; w < WAVES_PER_BLOCK; ++w) t += lsum[w];
    out[0] = t * scale;
  }
}

extern "C" void kernel_launch(void* const* d_in, const int* in_sizes, int n_in,
                              void* d_out, int out_size, void* d_ws, size_t ws_size,
                              hipStream_t stream) {
  const float* pred = (const float*)d_in[0];
  const int* target = (const int*)d_in[1];
  float* out = (float*)d_out;
  float* partial = (float*)d_ws;

  const int B = in_sizes[1];
  const int C = in_sizes[0] / B;

  hinge_rows_kernel<<<GRID1, BLOCK, 0, stream>>>(pred, target, partial, B, C);
  hinge_reduce_kernel<<<1, BLOCK, 0, stream>>>(partial, GRID1, out, 1.0f / (float)B);
}